// Round 8
// baseline (330.173 us; speedup 1.0000x reference)
//
#include <hip/hip_runtime.h>
#include <cstdint>
#include <cstddef>

// ---------------------------------------------------------------------------
// QuantizedLinear: out = x @ W^T + bias (affine-dequant int16-range weights)
// B=8192, IN=4096, OUT=4096. Dequant to bf16 in ws; 256x256 MFMA GEMM.
// R8 = R7 skeleton with MFMA 32x32x16 (2x FLOP/phase, better rate):
//   phase = [stage 1 K-half (4 gload); 12 ds_read_b128; barrier; lgkmcnt(0);
//            setprio; 16 MFMA 32x32x16; setprio; vmcnt(N); barrier]
//   128 phases (one per K-half), slot = phase&3 (4 slots x [256][32] bf16).
// Ledger: phase P stages half P+3 into slot (P+3)&3 (freed at P-1's lgkm
//   drain, published by P-1's end barrier). vmcnt(8) at every phase end =>
//   stages <= P-2 confirmed (half P+1, staged P-2, published 1 phase before
//   its read at P+1). Tail (phases 125-127 stage nothing): VM4/VM0/none,
//   matching issued-stage counts. Prologue stages h0-h2, vmcnt(8) => h0.
// Chunk-XOR LDS swizzle (conflicts=0, R3) + XCD block swizzle unchanged.
// Fragment layouts (32x32x16 bf16): A/B lane l: row|col=l&31, k=(l>>5)*8..+8
//   (natural doubled-K extension of verified 16x16x32); C/D: col=lane&31,
//   row=(reg&3)+8*(reg>>2)+4*(lane>>5)  [m74/m101 HW-verified].
// ---------------------------------------------------------------------------

#define B_DIM  8192
#define IN_DIM 4096
#define OUT_DIM 4096

typedef short    bf16x8 __attribute__((ext_vector_type(8)));
typedef float    f32x16 __attribute__((ext_vector_type(16)));
typedef uint16_t u16x8  __attribute__((ext_vector_type(8)));

__device__ __forceinline__ uint16_t f2bf(float f) {
  uint32_t u = __builtin_bit_cast(uint32_t, f);
  u += 0x7FFFu + ((u >> 16) & 1u);
  return (uint16_t)(u >> 16);
}

__device__ __forceinline__ void gload_lds16(const void* g, void* l) {
  __builtin_amdgcn_global_load_lds(
      (const __attribute__((address_space(1))) unsigned int*)g,
      (__attribute__((address_space(3))) unsigned int*)l,
      16, 0, 0);
}

// ---------------- prologue: conversions ----------------

__global__ void cvt_x_kernel(const float* __restrict__ x,
                             uint16_t* __restrict__ o) {
  size_t i = (size_t)blockIdx.x * blockDim.x + threadIdx.x;
  const float4* xv = (const float4*)x;
  float4 a = xv[i * 2], b = xv[i * 2 + 1];
  u16x8 r;
  r[0] = f2bf(a.x); r[1] = f2bf(a.y); r[2] = f2bf(a.z); r[3] = f2bf(a.w);
  r[4] = f2bf(b.x); r[5] = f2bf(b.y); r[6] = f2bf(b.z); r[7] = f2bf(b.w);
  ((u16x8*)o)[i] = r;
}

__global__ void cvt_w_kernel(const int* __restrict__ q,
                             uint16_t* __restrict__ o,
                             const float* __restrict__ sp,
                             const float* __restrict__ wminp) {
  size_t i = (size_t)blockIdx.x * blockDim.x + threadIdx.x;
  float s = *sp, wmin = *wminp;
  const int4* qv = (const int4*)q;
  int4 a = qv[i * 2], b = qv[i * 2 + 1];
  u16x8 r;
  r[0] = f2bf(fmaf((float)a.x + 32768.0f, s, wmin));
  r[1] = f2bf(fmaf((float)a.y + 32768.0f, s, wmin));
  r[2] = f2bf(fmaf((float)a.z + 32768.0f, s, wmin));
  r[3] = f2bf(fmaf((float)a.w + 32768.0f, s, wmin));
  r[4] = f2bf(fmaf((float)b.x + 32768.0f, s, wmin));
  r[5] = f2bf(fmaf((float)b.y + 32768.0f, s, wmin));
  r[6] = f2bf(fmaf((float)b.z + 32768.0f, s, wmin));
  r[7] = f2bf(fmaf((float)b.w + 32768.0f, s, wmin));
  ((u16x8*)o)[i] = r;
}

__global__ void cvt_bias_kernel(const int* __restrict__ qb,
                                float* __restrict__ o,
                                const float* __restrict__ bsp,
                                const float* __restrict__ bminp) {
  int i = blockIdx.x * blockDim.x + threadIdx.x;
  if (i < OUT_DIM)
    o[i] = fmaf((float)qb[i] + 32768.0f, *bsp, *bminp);
}

// ---------------- main GEMM ----------------

__global__ __launch_bounds__(512, 2) void gemm256_kernel(
    const uint16_t* __restrict__ A, const uint16_t* __restrict__ Bw,
    const float* __restrict__ bias, float* __restrict__ C) {
  __shared__ bf16x8 Asl[4][1024];  // 4 slots x 16 KiB ([256 rows][4 chunks])
  __shared__ bf16x8 Bsl[4][1024];

  const int tid  = threadIdx.x;
  const int wave = tid >> 6;
  const int lane = tid & 63;

  int bid = blockIdx.x;
  int swz = (bid & 7) * 64 + (bid >> 3);   // bijective, nwg=512
  const int bm = swz >> 4;
  const int bn = swz & 15;
  const int M0 = bm * 256, N0 = bn * 256;

  const int wm = wave >> 2, wn = wave & 3;   // 2M x 4N waves, 128x64 each
  const int l31 = lane & 31, l5 = lane >> 5;
  const int rho = (l31 >> 1) & 3;
  // element index in slot = row*4 + chunk'; chunk' = logical ^ rho
  const int aIdx0 = (wm * 128 + l31) * 4 + (l5 ^ rho);        // kk=0
  const int bIdx0 = (wn * 64 + l31) * 4 + (l5 ^ rho);         // kk=0
  // kk=1: logical chunk += 2 -> element index XOR 2 (chunk = low 2 bits)

  const int schunk = (lane & 3) ^ ((lane >> 3) & 3);  // source-side swizzle
  const uint16_t* aSrc =
      A + (size_t)(M0 + wave * 16 + (lane >> 2)) * IN_DIM + schunk * 8;
  const uint16_t* bSrc =
      Bw + (size_t)(N0 + wave * 16 + (lane >> 2)) * IN_DIM + schunk * 8;

  f32x16 acc[8];   // [mi*2+ni]: mi 0..3 (M 32-blocks), ni 0..1 (N 32-blocks)
#pragma unroll
  for (int i = 0; i < 8; ++i) acc[i] = (f32x16)(0.f);

#define STAGE_A(G, j)                                                       \
  gload_lds16(aSrc + (size_t)(j) * 128 * IN_DIM + (size_t)(G) * 32,         \
              (char*)&Asl[(G) & 3][0] + (j) * 8192 + wave * 1024)
#define STAGE_B(G, j)                                                       \
  gload_lds16(bSrc + (size_t)(j) * 128 * IN_DIM + (size_t)(G) * 32,         \
              (char*)&Bsl[(G) & 3][0] + (j) * 8192 + wave * 1024)
#define STAGE_HALF(G)                                                       \
  do { STAGE_A(G, 0); STAGE_A(G, 1); STAGE_B(G, 0); STAGE_B(G, 1); } while (0)

  // prologue: stage halves 0,1,2 (12 loads); vmcnt(8) => h0 landed; publish
  STAGE_HALF(0); STAGE_HALF(1); STAGE_HALF(2);
  asm volatile("s_waitcnt vmcnt(8)" ::: "memory");
  __builtin_amdgcn_s_barrier();
  __builtin_amdgcn_sched_barrier(0);

  bf16x8 Af[8], Bf[4];  // Af[mi*2+kk], Bf[ni*2+kk]

  // PHASE(slot s, stage stmt, end-wait stmt): consume one K-half
#define PHASE(s, STG, EW)                                                   \
  {                                                                         \
    STG;                                                                    \
    _Pragma("unroll")                                                       \
    for (int ni = 0; ni < 2; ++ni) {                                        \
      Bf[ni * 2 + 0] = Bsl[s][(bIdx0) + ni * 128];                          \
      Bf[ni * 2 + 1] = Bsl[s][(bIdx0 ^ 2) + ni * 128];                      \
    }                                                                       \
    _Pragma("unroll")                                                       \
    for (int mi = 0; mi < 4; ++mi) {                                        \
      Af[mi * 2 + 0] = Asl[s][(aIdx0) + mi * 128];                          \
      Af[mi * 2 + 1] = Asl[s][(aIdx0 ^ 2) + mi * 128];                      \
    }                                                                       \
    __builtin_amdgcn_s_barrier();                                           \
    asm volatile("s_waitcnt lgkmcnt(0)" ::: "memory");                      \
    __builtin_amdgcn_sched_barrier(0);                                      \
    __builtin_amdgcn_s_setprio(1);                                          \
    _Pragma("unroll")                                                       \
    for (int kk = 0; kk < 2; ++kk)                                          \
      _Pragma("unroll")                                                     \
      for (int mi = 0; mi < 4; ++mi)                                        \
        _Pragma("unroll")                                                   \
        for (int ni = 0; ni < 2; ++ni)                                      \
          acc[mi * 2 + ni] = __builtin_amdgcn_mfma_f32_32x32x16_bf16(       \
              Af[mi * 2 + kk], Bf[ni * 2 + kk], acc[mi * 2 + ni], 0, 0, 0); \
    __builtin_amdgcn_s_setprio(0);                                          \
    EW;                                                                     \
    __builtin_amdgcn_s_barrier();                                           \
    __builtin_amdgcn_sched_barrier(0);                                      \
  }

#define VM8 asm volatile("s_waitcnt vmcnt(8)" ::: "memory")
#define VM4 asm volatile("s_waitcnt vmcnt(4)" ::: "memory")
#define VM0 asm volatile("s_waitcnt vmcnt(0)" ::: "memory")
#define NOSTG ((void)0)
#define NOWAIT ((void)0)

  // main: u=0..30, phases 4u..4u+3 consume halves 4u..4u+3, stage 4u+3..4u+6
  for (int u = 0; u < 31; ++u) {
    const int G = 4 * u;
    PHASE(0, STAGE_HALF(G + 3), VM8);
    PHASE(1, STAGE_HALF(G + 4), VM8);
    PHASE(2, STAGE_HALF(G + 5), VM8);
    PHASE(3, STAGE_HALF(G + 6), VM8);
  }
  // tail u=31: phases 124..127 consume halves 124..127; only h127 staged
  PHASE(0, STAGE_HALF(127), VM8);
  PHASE(1, NOSTG, VM4);
  PHASE(2, NOSTG, VM0);
  PHASE(3, NOSTG, NOWAIT);

#undef PHASE
#undef VM8
#undef VM4
#undef VM0
#undef NOSTG
#undef NOWAIT
#undef STAGE_A
#undef STAGE_B
#undef STAGE_HALF

  // epilogue: 32x32 C/D layout: col=lane&31, row=(reg&3)+8*(reg>>2)+4*l5
#pragma unroll
  for (int ni = 0; ni < 2; ++ni) {
    const int col = N0 + wn * 64 + ni * 32 + l31;
    const float bv = bias[col];
#pragma unroll
    for (int mi = 0; mi < 4; ++mi) {
      const int rbase = M0 + wm * 128 + mi * 32 + 4 * l5;
      const f32x16 v = acc[mi * 2 + ni];
#pragma unroll
      for (int reg = 0; reg < 16; ++reg) {
        const int row = rbase + (reg & 3) + 8 * (reg >> 2);
        C[(size_t)row * OUT_DIM + col] = v[reg] + bv;
      }
    }
  }
}

// ---------------- naive fallback (only if ws too small) ----------------
__global__ void naive_ql_kernel(const float* __restrict__ x,
                                const int* __restrict__ qw,
                                const int* __restrict__ qb,
                                const float* sp, const float* wminp,
                                const float* bsp, const float* bminp,
                                float* __restrict__ out) {
  int o = blockIdx.x * blockDim.x + threadIdx.x;
  int b = blockIdx.y;
  float s = *sp, wmin = *wminp;
  const float* xr = x + (size_t)b * IN_DIM;
  const int* wrow = qw + (size_t)o * IN_DIM;
  float acc = 0.f;
  for (int k = 0; k < IN_DIM; ++k)
    acc += xr[k] * fmaf((float)wrow[k] + 32768.0f, s, wmin);
  out[(size_t)b * OUT_DIM + o] =
      acc + fmaf((float)qb[o] + 32768.0f, *bsp, *bminp);
}

// ---------------- launch ----------------
extern "C" void kernel_launch(void* const* d_in, const int* in_sizes, int n_in,
                              void* d_out, int out_size, void* d_ws,
                              size_t ws_size, hipStream_t stream) {
  const float* x      = (const float*)d_in[0];
  const int*   qw     = (const int*)d_in[1];
  const int*   qb     = (const int*)d_in[2];
  const float* scale  = (const float*)d_in[3];
  const float* wmin   = (const float*)d_in[4];
  const float* bscale = (const float*)d_in[5];
  const float* bmin   = (const float*)d_in[6];
  float* out = (float*)d_out;

  const size_t xb_bytes = (size_t)B_DIM * IN_DIM * 2;
  const size_t wb_bytes = (size_t)OUT_DIM * IN_DIM * 2;
  const size_t bias_bytes = (size_t)OUT_DIM * 4;

  if (ws_size < xb_bytes + wb_bytes + bias_bytes) {
    naive_ql_kernel<<<dim3(OUT_DIM / 256, B_DIM), 256, 0, stream>>>(
        x, qw, qb, scale, wmin, bscale, bmin, out);
    return;
  }

  uint16_t* Xb    = (uint16_t*)d_ws;
  uint16_t* Wb    = (uint16_t*)((char*)d_ws + xb_bytes);
  float*    biasf = (float*)((char*)d_ws + xb_bytes + wb_bytes);

  cvt_x_kernel<<<(B_DIM * (size_t)IN_DIM / 8 + 255) / 256, 256, 0, stream>>>(x, Xb);
  cvt_w_kernel<<<(OUT_DIM * (size_t)IN_DIM / 8 + 255) / 256, 256, 0, stream>>>(
      qw, Wb, scale, wmin);
  cvt_bias_kernel<<<(OUT_DIM + 255) / 256, 256, 0, stream>>>(qb, biasf, bscale,
                                                             bmin);

  gemm256_kernel<<<512, 512, 0, stream>>>(Xb, Wb, biasf, out);
}

// Round 9
// 306.860 us; speedup vs baseline: 1.0760x; 1.0760x over previous
//
#include <hip/hip_runtime.h>
#include <cstdint>
#include <cstddef>

// ---------------------------------------------------------------------------
// QuantizedLinear: out = x @ W^T + bias (affine-dequant int16-range weights)
// B=8192, IN=4096, OUT=4096. Dequant to bf16 in ws; 256x256 MFMA GEMM.
// R9 = R7 8-phase skeleton (16x16x32 MFMA, 4 K-half slots, chunk-XOR swizzle
// conflicts=0, XCD swizzle, setprio, vmcnt(4) cadence) MINUS the in-loop
// asm lgkmcnt(0) + sched_barrier(0) pins: the compiler now emits fine-grained
// counted lgkmcnt waits per MFMA operand (m97/r109), so MFMA starts while the
// block's LDS read queue is still draining -- hiding the ~400-cyc drain that
// made R7 phases 1300 cyc instead of ~900.
// Hazard ledger unchanged from R7 (all edges end-barrier-protected):
//   stage map: q0:A(4u+3) q1:B(4u+3) q2:A(4u+4) ... q7:B(4u+6), slot=(G)&3.
//   RAW stage->read: staged >=2 phases before read, vmcnt-confirmed >=1
//     phase before read, published by that phase's end barrier.
//   RAW read->mfma: compiler-inserted counted lgkmcnt per operand.
//   WAR read->restage: all reads of phase P complete by end of P's MFMA
//     cluster (every operand consumed) < barrier(P) < restage at P+2.
//   Tail: per-phase end-wait = vmcnt(4*stages outstanding) (R5-bug-proof).
// ---------------------------------------------------------------------------

#define B_DIM  8192
#define IN_DIM 4096
#define OUT_DIM 4096

typedef short    bf16x8 __attribute__((ext_vector_type(8)));
typedef float    f32x4  __attribute__((ext_vector_type(4)));
typedef uint16_t u16x8  __attribute__((ext_vector_type(8)));

__device__ __forceinline__ uint16_t f2bf(float f) {
  uint32_t u = __builtin_bit_cast(uint32_t, f);
  u += 0x7FFFu + ((u >> 16) & 1u);
  return (uint16_t)(u >> 16);
}

__device__ __forceinline__ void gload_lds16(const void* g, void* l) {
  __builtin_amdgcn_global_load_lds(
      (const __attribute__((address_space(1))) unsigned int*)g,
      (__attribute__((address_space(3))) unsigned int*)l,
      16, 0, 0);
}

// ---------------- prologue: conversions ----------------

__global__ void cvt_x_kernel(const float* __restrict__ x,
                             uint16_t* __restrict__ o) {
  size_t i = (size_t)blockIdx.x * blockDim.x + threadIdx.x;
  const float4* xv = (const float4*)x;
  float4 a = xv[i * 2], b = xv[i * 2 + 1];
  u16x8 r;
  r[0] = f2bf(a.x); r[1] = f2bf(a.y); r[2] = f2bf(a.z); r[3] = f2bf(a.w);
  r[4] = f2bf(b.x); r[5] = f2bf(b.y); r[6] = f2bf(b.z); r[7] = f2bf(b.w);
  ((u16x8*)o)[i] = r;
}

__global__ void cvt_w_kernel(const int* __restrict__ q,
                             uint16_t* __restrict__ o,
                             const float* __restrict__ sp,
                             const float* __restrict__ wminp) {
  size_t i = (size_t)blockIdx.x * blockDim.x + threadIdx.x;
  float s = *sp, wmin = *wminp;
  const int4* qv = (const int4*)q;
  int4 a = qv[i * 2], b = qv[i * 2 + 1];
  u16x8 r;
  r[0] = f2bf(fmaf((float)a.x + 32768.0f, s, wmin));
  r[1] = f2bf(fmaf((float)a.y + 32768.0f, s, wmin));
  r[2] = f2bf(fmaf((float)a.z + 32768.0f, s, wmin));
  r[3] = f2bf(fmaf((float)a.w + 32768.0f, s, wmin));
  r[4] = f2bf(fmaf((float)b.x + 32768.0f, s, wmin));
  r[5] = f2bf(fmaf((float)b.y + 32768.0f, s, wmin));
  r[6] = f2bf(fmaf((float)b.z + 32768.0f, s, wmin));
  r[7] = f2bf(fmaf((float)b.w + 32768.0f, s, wmin));
  ((u16x8*)o)[i] = r;
}

__global__ void cvt_bias_kernel(const int* __restrict__ qb,
                                float* __restrict__ o,
                                const float* __restrict__ bsp,
                                const float* __restrict__ bminp) {
  int i = blockIdx.x * blockDim.x + threadIdx.x;
  if (i < OUT_DIM)
    o[i] = fmaf((float)qb[i] + 32768.0f, *bsp, *bminp);
}

// ---------------- main GEMM ----------------

__global__ __launch_bounds__(512, 2) void gemm256_kernel(
    const uint16_t* __restrict__ A, const uint16_t* __restrict__ Bw,
    const float* __restrict__ bias, float* __restrict__ C) {
  __shared__ bf16x8 Asl[4][1024];  // 4 slots x 16 KiB ([256 rows][4 chunks])
  __shared__ bf16x8 Bsl[4][1024];

  const int tid  = threadIdx.x;
  const int wave = tid >> 6;
  const int lane = tid & 63;

  int bid = blockIdx.x;
  int swz = (bid & 7) * 64 + (bid >> 3);   // bijective, nwg=512
  const int bm = swz >> 4;
  const int bn = swz & 15;
  const int M0 = bm * 256, N0 = bn * 256;

  const int wm = wave >> 2, wn = wave & 3;
  const int l15 = lane & 15, l4 = lane >> 4;
  const int swk = l4 ^ ((l15 >> 1) & 3);          // read-side chunk swizzle
  const int aIdx = (wm * 128 + l15) * 4 + swk;    // + 64*i for A row-block i
  const int bIdx = (wn * 64 + l15) * 4 + swk;     // + 64*n for B col-block n

  const int schunk = (lane & 3) ^ ((lane >> 3) & 3);  // source-side swizzle
  const uint16_t* aSrc =
      A + (size_t)(M0 + wave * 16 + (lane >> 2)) * IN_DIM + schunk * 8;
  const uint16_t* bSrc =
      Bw + (size_t)(N0 + wave * 16 + (lane >> 2)) * IN_DIM + schunk * 8;

  f32x4 acc[8][4];
#pragma unroll
  for (int i = 0; i < 8; ++i)
#pragma unroll
    for (int j = 0; j < 4; ++j) acc[i][j] = (f32x4){0.f, 0.f, 0.f, 0.f};

#define STAGE_A(G, j)                                                       \
  gload_lds16(aSrc + (size_t)(j) * 128 * IN_DIM + (size_t)(G) * 32,         \
              (char*)&Asl[(G) & 3][0] + (j) * 8192 + wave * 1024)
#define STAGE_B(G, j)                                                       \
  gload_lds16(bSrc + (size_t)(j) * 128 * IN_DIM + (size_t)(G) * 32,         \
              (char*)&Bsl[(G) & 3][0] + (j) * 8192 + wave * 1024)

  // prologue: stage halves 0,1,2 (A+B each, 12 insts); vmcnt(8) => h0 landed
  STAGE_A(0, 0); STAGE_A(0, 1); STAGE_B(0, 0); STAGE_B(0, 1);
  STAGE_A(1, 0); STAGE_A(1, 1); STAGE_B(1, 0); STAGE_B(1, 1);
  STAGE_A(2, 0); STAGE_A(2, 1); STAGE_B(2, 0); STAGE_B(2, 1);
  asm volatile("s_waitcnt vmcnt(8)" ::: "memory");
  __builtin_amdgcn_s_barrier();
  __builtin_amdgcn_sched_barrier(0);

  bf16x8 Af[4], Bf[4];

  // PHASE(slot s, mf-base m0, LOADB, stage statement, end-wait statement)
  // No explicit lgkmcnt / sched_barrier: compiler emits counted lgkm waits
  // per MFMA operand, so MFMA overlaps the block-wide LDS read drain.
#define PHASE(s, m0, LOADB, STG, EW)                                        \
  {                                                                         \
    STG;                                                                    \
    if (LOADB) {                                                            \
      _Pragma("unroll")                                                     \
      for (int n = 0; n < 4; ++n) Bf[n] = Bsl[s][bIdx + 64 * n];            \
    }                                                                       \
    _Pragma("unroll")                                                       \
    for (int i = 0; i < 4; ++i) Af[i] = Asl[s][aIdx + 64 * ((m0) + i)];     \
    __builtin_amdgcn_s_barrier();                                           \
    __builtin_amdgcn_s_setprio(1);                                          \
    _Pragma("unroll")                                                       \
    for (int i = 0; i < 4; ++i)                                             \
      _Pragma("unroll")                                                     \
      for (int n = 0; n < 4; ++n)                                           \
        acc[(m0) + i][n] = __builtin_amdgcn_mfma_f32_16x16x32_bf16(         \
            Af[i], Bf[n], acc[(m0) + i][n], 0, 0, 0);                       \
    __builtin_amdgcn_s_setprio(0);                                          \
    EW;                                                                     \
    __builtin_amdgcn_s_barrier();                                           \
  }

#define VM4 asm volatile("s_waitcnt vmcnt(4)" ::: "memory")
#define VM0 asm volatile("s_waitcnt vmcnt(0)" ::: "memory")
#define NOWAIT ((void)0)

  for (int u = 0; u < 32; ++u) {
    const int G0 = 4 * u + 3, G1 = 4 * u + 4, G2 = 4 * u + 5, G3 = 4 * u + 6;
    const bool p1 = (G1 < 128), p2 = (G2 < 128), p3 = (G3 < 128);

    // q0: slot0, mf 0-3, load B; stage A(G0)->slot3
    PHASE(0, 0, true, { STAGE_A(G0, 0); STAGE_A(G0, 1); }, NOWAIT);
    // q1: slot0, mf 4-7; stage B(G0); vmcnt(4)
    PHASE(0, 4, false, { STAGE_B(G0, 0); STAGE_B(G0, 1); }, VM4);
    // q2: slot1, mf 0-3, load B; stage A(G1)->slot0
    PHASE(1, 0, true, { if (p1) { STAGE_A(G1, 0); STAGE_A(G1, 1); } }, NOWAIT);
    // q3: slot1, mf 4-7; stage B(G1); vmcnt(4 if staged else 0)
    PHASE(1, 4, false, { if (p1) { STAGE_B(G1, 0); STAGE_B(G1, 1); } },
          { if (p1) { VM4; } else { VM0; } });
    // q4: slot2, mf 0-3, load B; stage A(G2)->slot1
    PHASE(2, 0, true, { if (p2) { STAGE_A(G2, 0); STAGE_A(G2, 1); } }, NOWAIT);
    // q5: slot2, mf 4-7; stage B(G2)
    PHASE(2, 4, false, { if (p2) { STAGE_B(G2, 0); STAGE_B(G2, 1); } },
          { if (p2) { VM4; } else { VM0; } });
    // q6: slot3, mf 0-3, load B; stage A(G3)->slot2
    PHASE(3, 0, true, { if (p3) { STAGE_A(G3, 0); STAGE_A(G3, 1); } }, NOWAIT);
    // q7: slot3, mf 4-7; stage B(G3)
    PHASE(3, 4, false, { if (p3) { STAGE_B(G3, 0); STAGE_B(G3, 1); } },
          { if (p3) { VM4; } else { VM0; } });
  }
#undef PHASE
#undef VM4
#undef VM0
#undef NOWAIT
#undef STAGE_A
#undef STAGE_B

  // epilogue: C/D frag layout col=lane&15, row=(lane>>4)*4+j
  const int ccol = N0 + wn * 64 + l15;
#pragma unroll
  for (int nf = 0; nf < 4; ++nf) {
    float bv = bias[ccol + nf * 16];
#pragma unroll
    for (int mf = 0; mf < 8; ++mf) {
      const int r0 = M0 + wm * 128 + mf * 16 + l4 * 4;
#pragma unroll
      for (int j = 0; j < 4; ++j)
        C[(size_t)(r0 + j) * OUT_DIM + ccol + nf * 16] = acc[mf][nf][j] + bv;
    }
  }
}

// ---------------- naive fallback (only if ws too small) ----------------
__global__ void naive_ql_kernel(const float* __restrict__ x,
                                const int* __restrict__ qw,
                                const int* __restrict__ qb,
                                const float* sp, const float* wminp,
                                const float* bsp, const float* bminp,
                                float* __restrict__ out) {
  int o = blockIdx.x * blockDim.x + threadIdx.x;
  int b = blockIdx.y;
  float s = *sp, wmin = *wminp;
  const float* xr = x + (size_t)b * IN_DIM;
  const int* wrow = qw + (size_t)o * IN_DIM;
  float acc = 0.f;
  for (int k = 0; k < IN_DIM; ++k)
    acc += xr[k] * fmaf((float)wrow[k] + 32768.0f, s, wmin);
  out[(size_t)b * OUT_DIM + o] =
      acc + fmaf((float)qb[o] + 32768.0f, *bsp, *bminp);
}

// ---------------- launch ----------------
extern "C" void kernel_launch(void* const* d_in, const int* in_sizes, int n_in,
                              void* d_out, int out_size, void* d_ws,
                              size_t ws_size, hipStream_t stream) {
  const float* x      = (const float*)d_in[0];
  const int*   qw     = (const int*)d_in[1];
  const int*   qb     = (const int*)d_in[2];
  const float* scale  = (const float*)d_in[3];
  const float* wmin   = (const float*)d_in[4];
  const float* bscale = (const float*)d_in[5];
  const float* bmin   = (const float*)d_in[6];
  float* out = (float*)d_out;

  const size_t xb_bytes = (size_t)B_DIM * IN_DIM * 2;
  const size_t wb_bytes = (size_t)OUT_DIM * IN_DIM * 2;
  const size_t bias_bytes = (size_t)OUT_DIM * 4;

  if (ws_size < xb_bytes + wb_bytes + bias_bytes) {
    naive_ql_kernel<<<dim3(OUT_DIM / 256, B_DIM), 256, 0, stream>>>(
        x, qw, qb, scale, wmin, bscale, bmin, out);
    return;
  }

  uint16_t* Xb    = (uint16_t*)d_ws;
  uint16_t* Wb    = (uint16_t*)((char*)d_ws + xb_bytes);
  float*    biasf = (float*)((char*)d_ws + xb_bytes + wb_bytes);

  cvt_x_kernel<<<(B_DIM * (size_t)IN_DIM / 8 + 255) / 256, 256, 0, stream>>>(x, Xb);
  cvt_w_kernel<<<(OUT_DIM * (size_t)IN_DIM / 8 + 255) / 256, 256, 0, stream>>>(
      qw, Wb, scale, wmin);
  cvt_bias_kernel<<<(OUT_DIM + 255) / 256, 256, 0, stream>>>(qb, biasf, bscale,
                                                             bmin);

  gemm256_kernel<<<512, 512, 0, stream>>>(Xb, Wb, biasf, out);
}

// Round 10
// 303.102 us; speedup vs baseline: 1.0893x; 1.0124x over previous
//
#include <hip/hip_runtime.h>
#include <cstdint>
#include <cstddef>

// ---------------------------------------------------------------------------
// QuantizedLinear: out = x @ W^T + bias (affine-dequant int16-range weights)
// B=8192, IN=4096, OUT=4096. Dequant to bf16 in ws; 256x256 MFMA GEMM.
// R10 = R9 MINUS the mid-phase barrier, vmcnt(8) at odd-phase ends only:
//   phase = [stage 2 gload; 4-8 ds_read_b128; setprio; 16 MFMA (compiler
//            counted lgkm waits); setprio; {VM8 at odd phases}; end barrier]
// Hazard ledger:
//   WAR stage->prior readers: stage at P targets the slot whose readers all
//     consumed their data inside P-1 (MFMA operands) < P-1 end barrier < P.
//     End barriers bound skew to <=1 phase; every edge has >=1 barrier.
//   RAW stage->read (VM8 at q1/q3/q5/q7 ends): half staged (q0,q1) retired
//     by q5-end (12 issued, vmcnt(8) => oldest 4 landed), read q6/q7: 1-phase
//     margin. (q2,q3)->retired q7-end, read next q0. (q4,q5)->next q1-end,
//     read next q2. (q6,q7)->next q3-end, read next q4. Prologue: h0 by
//     vmcnt(8), h1 by q1-end, h2 by q3-end.
//   RAW read->mfma: compiler counted lgkmcnt per MFMA operand (R9-verified).
//   Tail u=31 (only half 127 staged at q0,q1): VM8@q1, VM0@q3 (2 phases
//     before half-127's q6 read), NOWAIT after -- stage-count-matched.
// Chunk-XOR LDS swizzle (conflicts=0) + XCD block swizzle + setprio kept.
// ---------------------------------------------------------------------------

#define B_DIM  8192
#define IN_DIM 4096
#define OUT_DIM 4096

typedef short    bf16x8 __attribute__((ext_vector_type(8)));
typedef float    f32x4  __attribute__((ext_vector_type(4)));
typedef uint16_t u16x8  __attribute__((ext_vector_type(8)));

__device__ __forceinline__ uint16_t f2bf(float f) {
  uint32_t u = __builtin_bit_cast(uint32_t, f);
  u += 0x7FFFu + ((u >> 16) & 1u);
  return (uint16_t)(u >> 16);
}

__device__ __forceinline__ void gload_lds16(const void* g, void* l) {
  __builtin_amdgcn_global_load_lds(
      (const __attribute__((address_space(1))) unsigned int*)g,
      (__attribute__((address_space(3))) unsigned int*)l,
      16, 0, 0);
}

// ---------------- prologue: conversions ----------------

__global__ void cvt_x_kernel(const float* __restrict__ x,
                             uint16_t* __restrict__ o) {
  size_t i = (size_t)blockIdx.x * blockDim.x + threadIdx.x;
  const float4* xv = (const float4*)x;
  float4 a = xv[i * 2], b = xv[i * 2 + 1];
  u16x8 r;
  r[0] = f2bf(a.x); r[1] = f2bf(a.y); r[2] = f2bf(a.z); r[3] = f2bf(a.w);
  r[4] = f2bf(b.x); r[5] = f2bf(b.y); r[6] = f2bf(b.z); r[7] = f2bf(b.w);
  ((u16x8*)o)[i] = r;
}

__global__ void cvt_w_kernel(const int* __restrict__ q,
                             uint16_t* __restrict__ o,
                             const float* __restrict__ sp,
                             const float* __restrict__ wminp) {
  size_t i = (size_t)blockIdx.x * blockDim.x + threadIdx.x;
  float s = *sp, wmin = *wminp;
  const int4* qv = (const int4*)q;
  int4 a = qv[i * 2], b = qv[i * 2 + 1];
  u16x8 r;
  r[0] = f2bf(fmaf((float)a.x + 32768.0f, s, wmin));
  r[1] = f2bf(fmaf((float)a.y + 32768.0f, s, wmin));
  r[2] = f2bf(fmaf((float)a.z + 32768.0f, s, wmin));
  r[3] = f2bf(fmaf((float)a.w + 32768.0f, s, wmin));
  r[4] = f2bf(fmaf((float)b.x + 32768.0f, s, wmin));
  r[5] = f2bf(fmaf((float)b.y + 32768.0f, s, wmin));
  r[6] = f2bf(fmaf((float)b.z + 32768.0f, s, wmin));
  r[7] = f2bf(fmaf((float)b.w + 32768.0f, s, wmin));
  ((u16x8*)o)[i] = r;
}

__global__ void cvt_bias_kernel(const int* __restrict__ qb,
                                float* __restrict__ o,
                                const float* __restrict__ bsp,
                                const float* __restrict__ bminp) {
  int i = blockIdx.x * blockDim.x + threadIdx.x;
  if (i < OUT_DIM)
    o[i] = fmaf((float)qb[i] + 32768.0f, *bsp, *bminp);
}

// ---------------- main GEMM ----------------

__global__ __launch_bounds__(512, 2) void gemm256_kernel(
    const uint16_t* __restrict__ A, const uint16_t* __restrict__ Bw,
    const float* __restrict__ bias, float* __restrict__ C) {
  __shared__ bf16x8 Asl[4][1024];  // 4 slots x 16 KiB ([256 rows][4 chunks])
  __shared__ bf16x8 Bsl[4][1024];

  const int tid  = threadIdx.x;
  const int wave = tid >> 6;
  const int lane = tid & 63;

  int bid = blockIdx.x;
  int swz = (bid & 7) * 64 + (bid >> 3);   // bijective, nwg=512
  const int bm = swz >> 4;
  const int bn = swz & 15;
  const int M0 = bm * 256, N0 = bn * 256;

  const int wm = wave >> 2, wn = wave & 3;
  const int l15 = lane & 15, l4 = lane >> 4;
  const int swk = l4 ^ ((l15 >> 1) & 3);          // read-side chunk swizzle
  const int aIdx = (wm * 128 + l15) * 4 + swk;    // + 64*i for A row-block i
  const int bIdx = (wn * 64 + l15) * 4 + swk;     // + 64*n for B col-block n

  const int schunk = (lane & 3) ^ ((lane >> 3) & 3);  // source-side swizzle
  const uint16_t* aSrc =
      A + (size_t)(M0 + wave * 16 + (lane >> 2)) * IN_DIM + schunk * 8;
  const uint16_t* bSrc =
      Bw + (size_t)(N0 + wave * 16 + (lane >> 2)) * IN_DIM + schunk * 8;

  f32x4 acc[8][4];
#pragma unroll
  for (int i = 0; i < 8; ++i)
#pragma unroll
    for (int j = 0; j < 4; ++j) acc[i][j] = (f32x4){0.f, 0.f, 0.f, 0.f};

#define STAGE_A(G, j)                                                       \
  gload_lds16(aSrc + (size_t)(j) * 128 * IN_DIM + (size_t)(G) * 32,         \
              (char*)&Asl[(G) & 3][0] + (j) * 8192 + wave * 1024)
#define STAGE_B(G, j)                                                       \
  gload_lds16(bSrc + (size_t)(j) * 128 * IN_DIM + (size_t)(G) * 32,         \
              (char*)&Bsl[(G) & 3][0] + (j) * 8192 + wave * 1024)

  // prologue: stage halves 0,1,2 (12 gloads); vmcnt(8) => h0 landed; publish
  STAGE_A(0, 0); STAGE_A(0, 1); STAGE_B(0, 0); STAGE_B(0, 1);
  STAGE_A(1, 0); STAGE_A(1, 1); STAGE_B(1, 0); STAGE_B(1, 1);
  STAGE_A(2, 0); STAGE_A(2, 1); STAGE_B(2, 0); STAGE_B(2, 1);
  asm volatile("s_waitcnt vmcnt(8)" ::: "memory");
  __builtin_amdgcn_s_barrier();
  __builtin_amdgcn_sched_barrier(0);

  bf16x8 Af[4], Bf[4];

  // PHASE: no mid barrier; compiler inserts counted lgkm waits per operand.
#define PHASE(s, m0, LOADB, STG, EW)                                        \
  {                                                                         \
    STG;                                                                    \
    if (LOADB) {                                                            \
      _Pragma("unroll")                                                     \
      for (int n = 0; n < 4; ++n) Bf[n] = Bsl[s][bIdx + 64 * n];            \
    }                                                                       \
    _Pragma("unroll")                                                       \
    for (int i = 0; i < 4; ++i) Af[i] = Asl[s][aIdx + 64 * ((m0) + i)];     \
    __builtin_amdgcn_s_setprio(1);                                          \
    _Pragma("unroll")                                                       \
    for (int i = 0; i < 4; ++i)                                             \
      _Pragma("unroll")                                                     \
      for (int n = 0; n < 4; ++n)                                           \
        acc[(m0) + i][n] = __builtin_amdgcn_mfma_f32_16x16x32_bf16(         \
            Af[i], Bf[n], acc[(m0) + i][n], 0, 0, 0);                       \
    __builtin_amdgcn_s_setprio(0);                                          \
    EW;                                                                     \
    __builtin_amdgcn_s_barrier();                                           \
  }

#define VM8 asm volatile("s_waitcnt vmcnt(8)" ::: "memory")
#define VM4 asm volatile("s_waitcnt vmcnt(4)" ::: "memory")
#define VM0 asm volatile("s_waitcnt vmcnt(0)" ::: "memory")
#define NOWAIT ((void)0)

  // main: u=0..30 (all halves staged)
  for (int u = 0; u < 31; ++u) {
    const int G0 = 4 * u + 3, G1 = 4 * u + 4, G2 = 4 * u + 5, G3 = 4 * u + 6;
    PHASE(0, 0, true,  { STAGE_A(G0, 0); STAGE_A(G0, 1); }, NOWAIT);
    PHASE(0, 4, false, { STAGE_B(G0, 0); STAGE_B(G0, 1); }, VM8);
    PHASE(1, 0, true,  { STAGE_A(G1, 0); STAGE_A(G1, 1); }, NOWAIT);
    PHASE(1, 4, false, { STAGE_B(G1, 0); STAGE_B(G1, 1); }, VM8);
    PHASE(2, 0, true,  { STAGE_A(G2, 0); STAGE_A(G2, 1); }, NOWAIT);
    PHASE(2, 4, false, { STAGE_B(G2, 0); STAGE_B(G2, 1); }, VM8);
    PHASE(3, 0, true,  { STAGE_A(G3, 0); STAGE_A(G3, 1); }, NOWAIT);
    PHASE(3, 4, false, { STAGE_B(G3, 0); STAGE_B(G3, 1); }, VM8);
  }
  // tail u=31: only half 127 staged (q0: A, q1: B); VM0@q3 => confirmed
  // 2 phases before its q6/q7 read; nothing outstanding afterwards.
  PHASE(0, 0, true,  { STAGE_A(127, 0); STAGE_A(127, 1); }, NOWAIT);
  PHASE(0, 4, false, { STAGE_B(127, 0); STAGE_B(127, 1); }, VM8);
  PHASE(1, 0, true,  NOWAIT, NOWAIT);
  PHASE(1, 4, false, NOWAIT, VM0);
  PHASE(2, 0, true,  NOWAIT, NOWAIT);
  PHASE(2, 4, false, NOWAIT, NOWAIT);
  PHASE(3, 0, true,  NOWAIT, NOWAIT);
  PHASE(3, 4, false, NOWAIT, NOWAIT);

#undef PHASE
#undef VM8
#undef VM4
#undef VM0
#undef NOWAIT
#undef STAGE_A
#undef STAGE_B

  // epilogue: C/D frag layout col=lane&15, row=(lane>>4)*4+j
  const int ccol = N0 + wn * 64 + l15;
#pragma unroll
  for (int nf = 0; nf < 4; ++nf) {
    float bv = bias[ccol + nf * 16];
#pragma unroll
    for (int mf = 0; mf < 8; ++mf) {
      const int r0 = M0 + wm * 128 + mf * 16 + l4 * 4;
#pragma unroll
      for (int j = 0; j < 4; ++j)
        C[(size_t)(r0 + j) * OUT_DIM + ccol + nf * 16] = acc[mf][nf][j] + bv;
    }
  }
}

// ---------------- naive fallback (only if ws too small) ----------------
__global__ void naive_ql_kernel(const float* __restrict__ x,
                                const int* __restrict__ qw,
                                const int* __restrict__ qb,
                                const float* sp, const float* wminp,
                                const float* bsp, const float* bminp,
                                float* __restrict__ out) {
  int o = blockIdx.x * blockDim.x + threadIdx.x;
  int b = blockIdx.y;
  float s = *sp, wmin = *wminp;
  const float* xr = x + (size_t)b * IN_DIM;
  const int* wrow = qw + (size_t)o * IN_DIM;
  float acc = 0.f;
  for (int k = 0; k < IN_DIM; ++k)
    acc += xr[k] * fmaf((float)wrow[k] + 32768.0f, s, wmin);
  out[(size_t)b * OUT_DIM + o] =
      acc + fmaf((float)qb[o] + 32768.0f, *bsp, *bminp);
}

// ---------------- launch ----------------
extern "C" void kernel_launch(void* const* d_in, const int* in_sizes, int n_in,
                              void* d_out, int out_size, void* d_ws,
                              size_t ws_size, hipStream_t stream) {
  const float* x      = (const float*)d_in[0];
  const int*   qw     = (const int*)d_in[1];
  const int*   qb     = (const int*)d_in[2];
  const float* scale  = (const float*)d_in[3];
  const float* wmin   = (const float*)d_in[4];
  const float* bscale = (const float*)d_in[5];
  const float* bmin   = (const float*)d_in[6];
  float* out = (float*)d_out;

  const size_t xb_bytes = (size_t)B_DIM * IN_DIM * 2;
  const size_t wb_bytes = (size_t)OUT_DIM * IN_DIM * 2;
  const size_t bias_bytes = (size_t)OUT_DIM * 4;

  if (ws_size < xb_bytes + wb_bytes + bias_bytes) {
    naive_ql_kernel<<<dim3(OUT_DIM / 256, B_DIM), 256, 0, stream>>>(
        x, qw, qb, scale, wmin, bscale, bmin, out);
    return;
  }

  uint16_t* Xb    = (uint16_t*)d_ws;
  uint16_t* Wb    = (uint16_t*)((char*)d_ws + xb_bytes);
  float*    biasf = (float*)((char*)d_ws + xb_bytes + wb_bytes);

  cvt_x_kernel<<<(B_DIM * (size_t)IN_DIM / 8 + 255) / 256, 256, 0, stream>>>(x, Xb);
  cvt_w_kernel<<<(OUT_DIM * (size_t)IN_DIM / 8 + 255) / 256, 256, 0, stream>>>(
      qw, Wb, scale, wmin);
  cvt_bias_kernel<<<(OUT_DIM + 255) / 256, 256, 0, stream>>>(qb, biasf, bscale,
                                                             bmin);

  gemm256_kernel<<<512, 512, 0, stream>>>(Xb, Wb, biasf, out);
}